// Round 11
// baseline (2915.521 us; speedup 1.0000x reference)
//
#include <hip/hip_runtime.h>
#include <float.h>
#include <math.h>

#define NTOK 16384
#define KCB  2048
#define DDIM 256
#define NCB  10
// Screening margin. Screen is a SINGLE bf16 MFMA pass: per-dist error rms
// ~2.9e-5, code-pair difference rms ~4.1e-5 (dominated by bf16 rounding of
// res and E). Hoeffding with realized per-term bounds (sum b^2 ~ 5e-9):
// P(miss) <= exp(-2*(5e-4)^2/5e-9) = e^-100 per comparison -> safe over all
// 3.3e8 comparisons. Candidates within margin are exact-evaluated with the
// bit-identical np FMA chain, so outputs are exact regardless.
#define MARGIN 5.0e-4f
#define OVF_FLAG (1 << 30)   // overflow marker in slot-3 code field (codes<2048)

typedef __attribute__((ext_vector_type(8))) short  short8;
typedef __attribute__((ext_vector_type(4))) float  f32x4;

static __device__ __forceinline__ unsigned short f2bf(float f) {
    unsigned int b = __float_as_uint(f);
    unsigned int r = b + 0x7FFFu + ((b >> 16) & 1u);   // RNE
    return (unsigned short)(r >> 16);
}

// ================= fused prep =================
// blocks [0,5120): E conv x4 + np-exact row norms (LDS bounce);
// [5120,9216): z conv x4 + norms; [9216,9472): w1t; [9472,10496): w2t.
__global__ __launch_bounds__(256) void prep_all(const float* __restrict__ E,
                                                const float* __restrict__ z,
                                                const float* __restrict__ W1,
                                                const float* __restrict__ W2,
                                                float* __restrict__ sseE,
                                                float* __restrict__ normA,
                                                unsigned short* __restrict__ Eh,
                                                unsigned short* __restrict__ resH,
                                                unsigned short* __restrict__ w1t,
                                                unsigned short* __restrict__ w2t) {
    const int b = blockIdx.x;
    if (b < 9216) {
        __shared__ float sRow[4][260];    // +pad: spread 4 groups across banks
        const float* src; unsigned short* dst; float* ndst; int i, row0;
        if (b < 5120) { src = E; dst = Eh;   ndst = sseE;  i = b * 256 + threadIdx.x;          row0 = b * 4; }
        else          { src = z; dst = resH; ndst = normA; i = (b - 5120) * 256 + threadIdx.x; row0 = (b - 5120) * 4; }
        float4 f = *(const float4*)(src + (size_t)i * 4);
        unsigned short h[4] = { f2bf(f.x), f2bf(f.y), f2bf(f.z), f2bf(f.w) };
        *(ushort4*)(dst + (size_t)i * 4) = *(ushort4*)h;
        {
            int r = threadIdx.x >> 6, c = (threadIdx.x & 63) * 4;
            *(float4*)&sRow[r][c] = f;
        }
        __syncthreads();
        if (threadIdx.x < 64) {           // wave 0: 4 rows x 16-lane groups
            const int l15 = threadIdx.x & 15, g = threadIdx.x >> 4;
            const float* a = &sRow[g][((l15 >> 3) << 7) + (l15 & 7)];
            float v = a[0];
            float r = __fmul_rn(v, v);
            #pragma unroll
            for (int k = 1; k < 16; ++k) { v = a[k * 8]; r = __fadd_rn(r, __fmul_rn(v, v)); }
            r = __fadd_rn(r, __shfl_xor(r, 1, 64));
            r = __fadd_rn(r, __shfl_xor(r, 2, 64));
            r = __fadd_rn(r, __shfl_xor(r, 4, 64));
            r = __fadd_rn(r, __shfl_xor(r, 8, 64));
            if (l15 == 0) ndst[row0 + g] = r;
        }
    } else if (b < 9472) {
        int j = (b - 9216) * 256 + threadIdx.x;
        int n = j >> 8, k = j & 255;
        w1t[j] = f2bf(W1[k * 256 + n]);
    } else {
        int j = (b - 9472) * 256 + threadIdx.x;
        int n = j >> 8, k = j & 255;
        w2t[j] = f2bf(W2[k * 1024 + n]);
    }
}

// ---- MFMA screening: round-10 structure (2048 blocks, 128x128 tile, dbuf B,
// A-register prefetch) + XCD-aware swizzle (each XCD owns 16 tiles x 16
// slices -> A rows and codebook L2-resident) + gCnt/gMin ELIMINATED (their
// 4B scattered stores were ~16x write-amplified). Overflow (cnt>4) is flagged
// in slot-3's code bit 30; post rescans on any flag. Slot SETS and MFMA
// values identical -> outputs bit-identical.
__global__ __launch_bounds__(256) void vq_screen(const unsigned short* __restrict__ resH,
                                                 const unsigned short* __restrict__ Ehi,
                                                 const float* __restrict__ sseEi,
                                                 int2* __restrict__ gSlots) {
    __shared__ unsigned short sBh[2][128 * 40];
    __shared__ float sC[128];
    __shared__ int   lCnt[128];
    __shared__ int2  lSlot[128][4];
    const int tid = threadIdx.x;
    const int wv = tid >> 6, lane = tid & 63;
    const int l15 = lane & 15, qd = lane >> 4;
    const int wid = (blockIdx.x & 7) * 256 + (blockIdx.x >> 3);   // XCD swizzle
    const int tile = wid >> 4, slice = wid & 15;
    const int t0 = tile * 128, c0 = slice * 128;

    if (tid < 128) { lCnt[tid] = 0; sC[tid] = sseEi[c0 + tid]; }
    {
        int2 inf; inf.x = 0x7F800000; inf.y = 0;
        ((int2*)lSlot)[tid] = inf; ((int2*)lSlot)[tid + 256] = inf;
    }

    f32x4 acc[2][8];
    #pragma unroll
    for (int m = 0; m < 2; ++m)
        #pragma unroll
        for (int n = 0; n < 8; ++n) acc[m][n] = (f32x4){0.f, 0.f, 0.f, 0.f};

    const size_t rowA0 = (size_t)(t0 + wv * 32 + l15) * 256 + qd * 8;
    short8 ah0 = *(const short8*)(resH + rowA0);
    short8 ah1 = *(const short8*)(resH + rowA0 + 16 * 256);
    #pragma unroll
    for (int jj = 0; jj < 2; ++jj) {
        int f = jj * 256 + tid;
        int r = f >> 2, cc = (f & 3) * 8;
        *(uint4*)(sBh[0] + r * 40 + cc) = *(const uint4*)(Ehi + (size_t)(c0 + r) * 256 + cc);
    }
    __syncthreads();

    for (int kc = 0; kc < 8; ++kc) {
        const int cur = kc & 1;
        short8 an0, an1;
        if (kc < 7) {
            const int dbn = (kc + 1) * 32;
            an0 = *(const short8*)(resH + rowA0 + dbn);
            an1 = *(const short8*)(resH + rowA0 + 16 * 256 + dbn);
            #pragma unroll
            for (int jj = 0; jj < 2; ++jj) {
                int f = jj * 256 + tid;
                int r = f >> 2, cc = (f & 3) * 8;
                *(uint4*)(sBh[cur ^ 1] + r * 40 + cc) =
                    *(const uint4*)(Ehi + (size_t)(c0 + r) * 256 + dbn + cc);
            }
        }
        #pragma unroll
        for (int n = 0; n < 8; ++n) {
            short8 bh = *(const short8*)(sBh[cur] + (n * 16 + l15) * 40 + qd * 8);
            acc[0][n] = __builtin_amdgcn_mfma_f32_16x16x32_bf16(ah0, bh, acc[0][n], 0, 0, 0);
            acc[1][n] = __builtin_amdgcn_mfma_f32_16x16x32_bf16(ah1, bh, acc[1][n], 0, 0, 0);
        }
        __syncthreads();
        if (kc < 7) { ah0 = an0; ah1 = an1; }
    }

    #pragma unroll
    for (int m = 0; m < 2; ++m)
        #pragma unroll
        for (int n = 0; n < 8; ++n) {
            float Cv = sC[n * 16 + l15];
            #pragma unroll
            for (int r = 0; r < 4; ++r) acc[m][n][r] = fmaf(-2.f, acc[m][n][r], Cv);
        }
    #pragma unroll
    for (int m = 0; m < 2; ++m)
        #pragma unroll
        for (int r = 0; r < 4; ++r) {
            float v = acc[m][0][r];
            #pragma unroll
            for (int n = 1; n < 8; ++n) v = fminf(v, acc[m][n][r]);
            v = fminf(v, __shfl_xor(v, 1, 64));
            v = fminf(v, __shfl_xor(v, 2, 64));
            v = fminf(v, __shfl_xor(v, 4, 64));
            v = fminf(v, __shfl_xor(v, 8, 64));
            int tloc = wv * 32 + m * 16 + qd * 4 + r;
            float thr = v + MARGIN;
            #pragma unroll
            for (int n = 0; n < 8; ++n) {
                float sv = acc[m][n][r];
                if (sv <= thr) {
                    int pos = atomicAdd(&lCnt[tloc], 1);
                    if (pos < 4) {
                        int2 e; e.x = __float_as_int(sv); e.y = c0 + n * 16 + l15;
                        lSlot[tloc][pos] = e;
                    }
                }
            }
        }
    __syncthreads();
    {
        int tloc = tid >> 1, half = tid & 1;
        size_t base = (size_t)(t0 + tloc) * 64 + slice * 4 + half * 2;
        int2 s0 = lSlot[tloc][half * 2];
        int2 s1 = lSlot[tloc][half * 2 + 1];
        if (half && lCnt[tloc] > 4) s1.y |= OVF_FLAG;   // slot 3 carries the flag
        gSlots[base]     = s0;
        gSlots[base + 1] = s1;
    }
}

// ---- exact np chain (per-lane, row from LDS copy of res) ----
static __device__ __forceinline__ float np_chain(const float* __restrict__ sRow,
                                                 const float* __restrict__ Ei,
                                                 int cc, float A, float C) {
    const float4* e = (const float4*)(Ei + (size_t)cc * DDIM);
    float a = 0.f;
    #pragma unroll 8
    for (int k = 0; k < 64; ++k) {
        float4 ev = e[k];
        const float4 rv = *(const float4*)(sRow + k * 4);
        a = fmaf(rv.x, ev.x, a); a = fmaf(rv.y, ev.y, a);
        a = fmaf(rv.z, ev.z, a); a = fmaf(rv.w, ev.w, a);
    }
    return __fadd_rn(fmaf(-2.f, a, A), C);
}

// ---- finalize: 1024 blocks x 4 waves x 4 tokens/wave ----
// gm now reduced over the 64 slot svs (identical value to the old gMin-based
// reduce in every non-rescan case); rescan on any overflow flag.
__global__ __launch_bounds__(256) void vq_post(const float* __restrict__ resSrc,
                                               const float* __restrict__ Ei,
                                               const float* __restrict__ sseEi,
                                               float* __restrict__ res,
                                               float* __restrict__ zq,
                                               float* __restrict__ codes,
                                               float* __restrict__ lossPart,
                                               float* __restrict__ normA,
                                               unsigned short* __restrict__ resHp,
                                               unsigned short* __restrict__ zqb,
                                               const int2* __restrict__ gSlots,
                                               int iter) {
    __shared__ float sScr[4][4][256];
    const int tid = threadIdx.x;
    const int wv = tid >> 6, lane = tid & 63;
    const int g = lane >> 4, l15 = lane & 15;
    const int tb = blockIdx.x * 16 + wv * 4;
    float lsum = 0.f;

    // phase 1: all independent loads
    int2 sl[4]; float4 r4[4]; float4 zq4[4]; float A4[4];
    #pragma unroll
    for (int j = 0; j < 4; ++j) sl[j] = gSlots[(size_t)(tb + j) * 64 + lane];
    #pragma unroll
    for (int j = 0; j < 4; ++j)
        r4[j] = *(const float4*)(resSrc + (size_t)(tb + j) * DDIM + lane * 4);
    #pragma unroll
    for (int j = 0; j < 4; ++j) A4[j] = normA[tb + j];
    if (iter > 0) {
        #pragma unroll
        for (int j = 0; j < 4; ++j)
            zq4[j] = *(const float4*)(zq + (size_t)(tb + j) * DDIM + lane * 4);
    }

    // phase 2: winners
    int winner[4];
    #pragma unroll
    for (int j = 0; j < 4; ++j) {
        const float sv = __int_as_float(sl[j].x);
        float gm = sv;
        #pragma unroll
        for (int o = 32; o >= 1; o >>= 1) gm = fminf(gm, __shfl_xor(gm, o, 64));
        const float thr = gm + MARGIN;
        const bool ovf = __any(((lane & 3) == 3 && (sl[j].y & OVF_FLAG)) ? 1 : 0);
        unsigned long long bal = __ballot((sv <= thr) ? 1 : 0);
        if (!ovf && __popcll(bal) == 1) {
            winner[j] = __shfl(sl[j].y, __ffsll(bal) - 1, 64);
        } else if (!ovf) {
            // lane-parallel exact eval of candidates
            *(float4*)(&sScr[wv][j][lane * 4]) = r4[j];
            const bool qal = (sv <= thr);
            const int cc = qal ? sl[j].y : 0;
            float s = np_chain(sScr[wv][j], Ei, cc, A4[j], sseEi[cc]);
            unsigned long long best = qal
                ? (((unsigned long long)__float_as_uint(s) << 32) | (unsigned)cc)
                : ~0ULL;
            #pragma unroll
            for (int o = 32; o >= 1; o >>= 1) {
                unsigned long long ot = __shfl_xor(best, o, 64);
                if (ot < best) best = ot;
            }
            winner[j] = (int)(unsigned)(best & 0xFFFFFFFFu);
        } else {
            // rare: full exact rescan
            *(float4*)(&sScr[wv][j][lane * 4]) = r4[j];
            unsigned long long best = ~0ULL;
            for (int cc = lane; cc < KCB; cc += 64) {
                float s = np_chain(sScr[wv][j], Ei, cc, A4[j], sseEi[cc]);
                unsigned long long key =
                    ((unsigned long long)__float_as_uint(s) << 32) | (unsigned)cc;
                if (key < best) best = key;
            }
            #pragma unroll
            for (int o = 32; o >= 1; o >>= 1) {
                unsigned long long ot = __shfl_xor(best, o, 64);
                if (ot < best) best = ot;
            }
            winner[j] = (int)(unsigned)(best & 0xFFFFFFFFu);
        }
    }
    #pragma unroll
    for (int j = 0; j < 4; ++j)
        if (lane == j) codes[(size_t)(tb + j) * NCB + iter] = (float)winner[j];

    // phase 3: concurrent gathers
    float4 q4[4];
    #pragma unroll
    for (int j = 0; j < 4; ++j)
        q4[j] = *(const float4*)(Ei + (size_t)winner[j] * DDIM + lane * 4);

    // phase 4: exact chain update + stores
    #pragma unroll
    for (int j = 0; j < 4; ++j) {
        const size_t go = (size_t)(tb + j) * DDIM + lane * 4;
        float4 rn4, zqi4;
        float tqx = q4[j].x - r4[j].x; zqi4.x = r4[j].x + tqx; rn4.x = r4[j].x - zqi4.x;
        float tqy = q4[j].y - r4[j].y; zqi4.y = r4[j].y + tqy; rn4.y = r4[j].y - zqi4.y;
        float tqz = q4[j].z - r4[j].z; zqi4.z = r4[j].z + tqz; rn4.z = r4[j].z - zqi4.z;
        float tqw = q4[j].w - r4[j].w; zqi4.w = r4[j].w + tqw; rn4.w = r4[j].w - zqi4.w;
        lsum = fmaf(tqx, tqx, lsum); lsum = fmaf(tqy, tqy, lsum);
        lsum = fmaf(tqz, tqz, lsum); lsum = fmaf(tqw, tqw, lsum);
        *(float4*)(res + go) = rn4;
        {
            unsigned short h[4] = { f2bf(rn4.x), f2bf(rn4.y), f2bf(rn4.z), f2bf(rn4.w) };
            *(ushort4*)(resHp + go) = *(ushort4*)h;
        }
        if (iter == 0) {
            *(float4*)(zq + go) = zqi4;
            unsigned short u[4] = { f2bf(zqi4.x), f2bf(zqi4.y), f2bf(zqi4.z), f2bf(zqi4.w) };
            *(ushort4*)(zqb + go) = *(ushort4*)u;
        } else {
            zq4[j].x += zqi4.x; zq4[j].y += zqi4.y;
            zq4[j].z += zqi4.z; zq4[j].w += zqi4.w;
            *(float4*)(zq + go) = zq4[j];
        }
        *(float4*)(&sScr[wv][j][lane * 4]) = rn4;
    }
    // phase 5: np-exact norms, 4 tokens in parallel (16-lane group g -> token tb+g)
    {
        const float* a = &sScr[wv][g][((l15 >> 3) << 7) + (l15 & 7)];
        float v = a[0];
        float r = __fmul_rn(v, v);
        #pragma unroll
        for (int k = 1; k < 16; ++k) { v = a[k * 8]; r = __fadd_rn(r, __fmul_rn(v, v)); }
        r = __fadd_rn(r, __shfl_xor(r, 1, 64));
        r = __fadd_rn(r, __shfl_xor(r, 2, 64));
        r = __fadd_rn(r, __shfl_xor(r, 4, 64));
        r = __fadd_rn(r, __shfl_xor(r, 8, 64));
        if (l15 == 0) normA[tb + g] = r;
    }
    #pragma unroll
    for (int o = 32; o >= 1; o >>= 1) lsum += __shfl_xor(lsum, o, 64);
    if (lane == 0) lossPart[iter * 4096 + blockIdx.x * 4 + wv] = lsum;
}

// ---- semantic head (round-6 proven 46us): 512 blocks = 256 grp x 2 halves
__global__ __launch_bounds__(256) void sem_mfma(const unsigned short* __restrict__ zqb,
                                                const float* __restrict__ tgt,
                                                const unsigned short* __restrict__ w1t,
                                                const float* __restrict__ b1,
                                                const unsigned short* __restrict__ w2t,
                                                const float* __restrict__ b2,
                                                float* __restrict__ semPart) {
    __shared__ uint4 sBq[2048];   // 32 KiB
    __shared__ uint4 sHq[2048];   // 32 KiB
    char* sBb = (char*)sBq;
    char* sHb = (char*)sHq;
    const int tid = threadIdx.x;
    const int wv = tid >> 6, lane = tid & 63;
    const int l15 = lane & 15, qd = lane >> 4;
    const int tb = (blockIdx.x >> 1) * 64;
    const int oh = blockIdx.x & 1;
    const int rs = tid >> 5, cs = tid & 31;
    const int swzs = (cs * 16) ^ ((rs & 7) << 4);

    #pragma unroll
    for (int j = 0; j < 8; ++j) {
        int r = j * 8 + rs;
        *(uint4*)(sHb + r * 512 + swzs) = *(const uint4*)(zqb + (size_t)(tb + r) * 256 + cs * 8);
    }
    __syncthreads();
    short8 az[8];
    {
        const int R = wv * 16 + l15;
        #pragma unroll
        for (int kc = 0; kc < 8; ++kc)
            az[kc] = *(const short8*)(sHb + R * 512 + ((kc * 64 + qd * 16) ^ ((R & 7) << 4)));
    }
    __syncthreads();

    #pragma unroll 1
    for (int s1 = 0; s1 < 4; ++s1) {
        #pragma unroll
        for (int j = 0; j < 8; ++j) {
            int r = j * 8 + rs;
            *(uint4*)(sBb + r * 512 + swzs) = *(const uint4*)(w1t + (size_t)(s1 * 64 + r) * 256 + cs * 8);
        }
        __syncthreads();
        f32x4 acc[4];
        #pragma unroll
        for (int n = 0; n < 4; ++n) acc[n] = (f32x4){0.f, 0.f, 0.f, 0.f};
        for (int kc = 0; kc < 8; ++kc) {
            #pragma unroll
            for (int n = 0; n < 4; ++n) {
                const int R = n * 16 + l15;
                short8 b = *(const short8*)(sBb + R * 512 + ((kc * 64 + qd * 16) ^ ((R & 7) << 4)));
                acc[n] = __builtin_amdgcn_mfma_f32_16x16x32_bf16(az[kc], b, acc[n], 0, 0, 0);
            }
        }
        #pragma unroll
        for (int n = 0; n < 4; ++n) {
            const int o = s1 * 64 + n * 16 + l15;
            const float b1v = b1[o];
            #pragma unroll
            for (int r = 0; r < 4; ++r) {
                float x = acc[n][r] + b1v;
                const int tr = wv * 16 + qd * 4 + r;
                *(unsigned short*)(sHb + tr * 512 + ((o * 2) ^ ((tr & 7) << 4))) =
                    f2bf(0.5f * x * (1.f + erff(x * 0.70710678f)));
            }
        }
        __syncthreads();
    }

    short8 ah[8];
    {
        const int R = wv * 16 + l15;
        #pragma unroll
        for (int kc = 0; kc < 8; ++kc)
            ah[kc] = *(const short8*)(sHb + R * 512 + ((kc * 64 + qd * 16) ^ ((R & 7) << 4)));
    }
    #pragma unroll
    for (int j = 0; j < 8; ++j) {
        int r = j * 8 + rs;
        *(uint4*)(sBb + r * 512 + swzs) = *(const uint4*)(w2t + (size_t)(oh * 512 + r) * 256 + cs * 8);
    }
    __syncthreads();

    float lsum = 0.f;
    #pragma unroll 1
    for (int s2 = 0; s2 < 8; ++s2) {
        const int gs = oh * 8 + s2;
        char* cb = (s2 & 1) ? sHb : sBb;
        char* nb = (s2 & 1) ? sBb : sHb;
        if (s2 < 7) {
            #pragma unroll
            for (int j = 0; j < 8; ++j) {
                int r = j * 8 + rs;
                *(uint4*)(nb + r * 512 + swzs) =
                    *(const uint4*)(w2t + (size_t)((gs + 1) * 64 + r) * 256 + cs * 8);
            }
        }
        float tg[4][4], b2v[4];
        #pragma unroll
        for (int n = 0; n < 4; ++n) {
            const int o = gs * 64 + n * 16 + l15;
            b2v[n] = b2[o];
            #pragma unroll
            for (int r = 0; r < 4; ++r)
                tg[n][r] = tgt[(size_t)(tb + wv * 16 + qd * 4 + r) * 1024 + o];
        }
        f32x4 acc[4];
        #pragma unroll
        for (int n = 0; n < 4; ++n) acc[n] = (f32x4){0.f, 0.f, 0.f, 0.f};
        for (int kc = 0; kc < 8; ++kc) {
            #pragma unroll
            for (int n = 0; n < 4; ++n) {
                const int R = n * 16 + l15;
                short8 b = *(const short8*)(cb + R * 512 + ((kc * 64 + qd * 16) ^ ((R & 7) << 4)));
                acc[n] = __builtin_amdgcn_mfma_f32_16x16x32_bf16(ah[kc], b, acc[n], 0, 0, 0);
            }
        }
        #pragma unroll
        for (int n = 0; n < 4; ++n)
            #pragma unroll
            for (int r = 0; r < 4; ++r) {
                float dv = (acc[n][r] + b2v[n]) - tg[n][r];
                lsum = fmaf(dv, dv, lsum);
            }
        __syncthreads();
    }
    #pragma unroll
    for (int o = 32; o >= 1; o >>= 1) lsum += __shfl_xor(lsum, o, 64);
    if (lane == 0) semPart[blockIdx.x * 4 + wv] = lsum;
}

// ---- loss finalize: vq (40960 wave partials) + semantic (2048 wave partials)
__global__ __launch_bounds__(256) void loss_final(const float* __restrict__ lossPart,
                                                  const float* __restrict__ semPart,
                                                  float* __restrict__ vql) {
    __shared__ float sRed[4], sRed2[4];
    float s = 0.f, q = 0.f;
    for (int i = threadIdx.x; i < 40960; i += 256) s += lossPart[i];
    for (int i = threadIdx.x; i < 2048; i += 256) q += semPart[i];
    #pragma unroll
    for (int o = 32; o >= 1; o >>= 1) { s += __shfl_xor(s, o, 64); q += __shfl_xor(q, o, 64); }
    if ((threadIdx.x & 63) == 0) { sRed[threadIdx.x >> 6] = s; sRed2[threadIdx.x >> 6] = q; }
    __syncthreads();
    if (threadIdx.x == 0) {
        vql[0] = (sRed[0] + sRed[1] + sRed[2] + sRed[3]) * (1.25f / 4194304.f);
        vql[1] = (sRed2[0] + sRed2[1] + sRed2[2] + sRed2[3]) * (1.0f / 16777216.f);
    }
}

extern "C" void kernel_launch(void* const* d_in, const int* in_sizes, int n_in,
                              void* d_out, int out_size, void* d_ws, size_t ws_size,
                              hipStream_t stream) {
    const float* z   = (const float*)d_in[0];
    const float* tgt = (const float*)d_in[1];
    const float* E   = (const float*)d_in[2];
    const float* W1  = (const float*)d_in[3];
    const float* b1  = (const float*)d_in[4];
    const float* W2  = (const float*)d_in[5];
    const float* b2  = (const float*)d_in[6];

    float* out   = (float*)d_out;
    float* zq    = out;
    float* codes = out + (size_t)NTOK * DDIM;
    float* vql   = codes + (size_t)NTOK * NCB;       // [vq_loss, semantic_loss]

    char* w = (char*)d_ws;
    float*          res   = (float*)(w);                         // 16 MiB
    unsigned short* resH  = (unsigned short*)(w + 16777216);     // 8 MiB
    float*          semPart=(float*)(w + 25165824);              // 8 KiB (old resL hole)
    unsigned short* Eh    = (unsigned short*)(w + 33554432);     // 10 MiB
    unsigned short* zqb   = (unsigned short*)(w + 54525952);     // 8 MiB
    int2*           gSlots= (int2*)(w + 62914560);               // 8 MiB
    float*          sseE  = (float*)(w + 73400320);              // 80 KiB (pad 128K)
    float*          normA = (float*)(w + 73531392);              // 64 KiB (pad 128K)
    float*          lossPart=(float*)(w + 73662464);             // 160 KiB (pad 256K)
    unsigned short* w1t   = (unsigned short*)(w + 73924608);     // 128 KiB
    unsigned short* w2t   = (unsigned short*)(w + 74055680);     // 512 KiB -> end 74579968

    prep_all<<<10496, 256, 0, stream>>>(E, z, W1, W2, sseE, normA, Eh, resH, w1t, w2t);
    for (int it = 0; it < NCB; ++it) {
        const float*          Ei    = E  + (size_t)it * KCB * DDIM;
        const unsigned short* Ehi   = Eh + (size_t)it * KCB * DDIM;
        const float*          sseEi = sseE + (size_t)it * KCB;
        const float* resSrc = (it == 0) ? z : res;
        vq_screen<<<2048, 256, 0, stream>>>(resH, Ehi, sseEi, gSlots);
        vq_post<<<1024, 256, 0, stream>>>(resSrc, Ei, sseEi, res, zq, codes, lossPart,
                                          normA, resH, zqb, gSlots, it);
        if (it == 0)
            sem_mfma<<<512, 256, 0, stream>>>(zqb, tgt, w1t, b1, w2t, b2, semPart);
    }
    loss_final<<<1, 256, 0, stream>>>(lossPart, semPart, vql);
}

// Round 12
// 909.765 us; speedup vs baseline: 3.2047x; 3.2047x over previous
//
#include <hip/hip_runtime.h>
#include <float.h>
#include <math.h>

#define NTOK 16384
#define KCB  2048
#define DDIM 256
#define NCB  10
// Screening margin. Screen is a SINGLE bf16 MFMA pass: per-dist error rms
// ~2.9e-5, code-pair difference rms ~4.1e-5 (dominated by bf16 rounding of
// res and E). Hoeffding with realized per-term bounds (sum b^2 ~ 5e-9):
// P(miss) <= exp(-2*(5e-4)^2/5e-9) = e^-100 per comparison -> safe over all
// 3.3e8 comparisons. Candidates within margin are exact-evaluated with the
// bit-identical np FMA chain, so outputs are exact regardless.
#define MARGIN 5.0e-4f
#define OVF_FLAG (1 << 30)   // overflow marker in slot-3 code field (codes<2048)

typedef __attribute__((ext_vector_type(8))) short  short8;
typedef __attribute__((ext_vector_type(4))) float  f32x4;

static __device__ __forceinline__ unsigned short f2bf(float f) {
    unsigned int b = __float_as_uint(f);
    unsigned int r = b + 0x7FFFu + ((b >> 16) & 1u);   // RNE
    return (unsigned short)(r >> 16);
}

// ================= fused prep =================
// blocks [0,5120): E conv x4 + np-exact row norms (LDS bounce);
// [5120,9216): z conv x4 + norms; [9216,9472): w1t; [9472,10496): w2t.
__global__ __launch_bounds__(256) void prep_all(const float* __restrict__ E,
                                                const float* __restrict__ z,
                                                const float* __restrict__ W1,
                                                const float* __restrict__ W2,
                                                float* __restrict__ sseE,
                                                float* __restrict__ normA,
                                                unsigned short* __restrict__ Eh,
                                                unsigned short* __restrict__ resH,
                                                unsigned short* __restrict__ w1t,
                                                unsigned short* __restrict__ w2t) {
    const int b = blockIdx.x;
    if (b < 9216) {
        __shared__ float sRow[4][260];    // +pad: spread 4 groups across banks
        const float* src; unsigned short* dst; float* ndst; int i, row0;
        if (b < 5120) { src = E; dst = Eh;   ndst = sseE;  i = b * 256 + threadIdx.x;          row0 = b * 4; }
        else          { src = z; dst = resH; ndst = normA; i = (b - 5120) * 256 + threadIdx.x; row0 = (b - 5120) * 4; }
        float4 f = *(const float4*)(src + (size_t)i * 4);
        unsigned short h[4] = { f2bf(f.x), f2bf(f.y), f2bf(f.z), f2bf(f.w) };
        *(ushort4*)(dst + (size_t)i * 4) = *(ushort4*)h;
        {
            int r = threadIdx.x >> 6, c = (threadIdx.x & 63) * 4;
            *(float4*)&sRow[r][c] = f;
        }
        __syncthreads();
        if (threadIdx.x < 64) {           // wave 0: 4 rows x 16-lane groups
            const int l15 = threadIdx.x & 15, g = threadIdx.x >> 4;
            const float* a = &sRow[g][((l15 >> 3) << 7) + (l15 & 7)];
            float v = a[0];
            float r = __fmul_rn(v, v);
            #pragma unroll
            for (int k = 1; k < 16; ++k) { v = a[k * 8]; r = __fadd_rn(r, __fmul_rn(v, v)); }
            r = __fadd_rn(r, __shfl_xor(r, 1, 64));
            r = __fadd_rn(r, __shfl_xor(r, 2, 64));
            r = __fadd_rn(r, __shfl_xor(r, 4, 64));
            r = __fadd_rn(r, __shfl_xor(r, 8, 64));
            if (l15 == 0) ndst[row0 + g] = r;
        }
    } else if (b < 9472) {
        int j = (b - 9216) * 256 + threadIdx.x;
        int n = j >> 8, k = j & 255;
        w1t[j] = f2bf(W1[k * 256 + n]);
    } else {
        int j = (b - 9472) * 256 + threadIdx.x;
        int n = j >> 8, k = j & 255;
        w2t[j] = f2bf(W2[k * 1024 + n]);
    }
}

// ---- MFMA screening: round-10 structure (2048 blocks, 128x128 tile, dbuf B,
// A-register prefetch) + XCD-aware swizzle + gCnt/gMin eliminated (their 4B
// scattered stores were ~16x write-amplified). Overflow (cnt>4) flagged in
// slot-3's code bit 30. Slot SETS and MFMA values identical -> bit-identical.
__global__ __launch_bounds__(256) void vq_screen(const unsigned short* __restrict__ resH,
                                                 const unsigned short* __restrict__ Ehi,
                                                 const float* __restrict__ sseEi,
                                                 int2* __restrict__ gSlots) {
    __shared__ unsigned short sBh[2][128 * 40];
    __shared__ float sC[128];
    __shared__ int   lCnt[128];
    __shared__ int2  lSlot[128][4];
    const int tid = threadIdx.x;
    const int wv = tid >> 6, lane = tid & 63;
    const int l15 = lane & 15, qd = lane >> 4;
    const int wid = (blockIdx.x & 7) * 256 + (blockIdx.x >> 3);   // XCD swizzle
    const int tile = wid >> 4, slice = wid & 15;
    const int t0 = tile * 128, c0 = slice * 128;

    if (tid < 128) { lCnt[tid] = 0; sC[tid] = sseEi[c0 + tid]; }
    {
        int2 inf; inf.x = 0x7F800000; inf.y = 0;
        ((int2*)lSlot)[tid] = inf; ((int2*)lSlot)[tid + 256] = inf;
    }

    f32x4 acc[2][8];
    #pragma unroll
    for (int m = 0; m < 2; ++m)
        #pragma unroll
        for (int n = 0; n < 8; ++n) acc[m][n] = (f32x4){0.f, 0.f, 0.f, 0.f};

    const size_t rowA0 = (size_t)(t0 + wv * 32 + l15) * 256 + qd * 8;
    short8 ah0 = *(const short8*)(resH + rowA0);
    short8 ah1 = *(const short8*)(resH + rowA0 + 16 * 256);
    #pragma unroll
    for (int jj = 0; jj < 2; ++jj) {
        int f = jj * 256 + tid;
        int r = f >> 2, cc = (f & 3) * 8;
        *(uint4*)(sBh[0] + r * 40 + cc) = *(const uint4*)(Ehi + (size_t)(c0 + r) * 256 + cc);
    }
    __syncthreads();

    for (int kc = 0; kc < 8; ++kc) {
        const int cur = kc & 1;
        short8 an0, an1;
        if (kc < 7) {
            const int dbn = (kc + 1) * 32;
            an0 = *(const short8*)(resH + rowA0 + dbn);
            an1 = *(const short8*)(resH + rowA0 + 16 * 256 + dbn);
            #pragma unroll
            for (int jj = 0; jj < 2; ++jj) {
                int f = jj * 256 + tid;
                int r = f >> 2, cc = (f & 3) * 8;
                *(uint4*)(sBh[cur ^ 1] + r * 40 + cc) =
                    *(const uint4*)(Ehi + (size_t)(c0 + r) * 256 + dbn + cc);
            }
        }
        #pragma unroll
        for (int n = 0; n < 8; ++n) {
            short8 bh = *(const short8*)(sBh[cur] + (n * 16 + l15) * 40 + qd * 8);
            acc[0][n] = __builtin_amdgcn_mfma_f32_16x16x32_bf16(ah0, bh, acc[0][n], 0, 0, 0);
            acc[1][n] = __builtin_amdgcn_mfma_f32_16x16x32_bf16(ah1, bh, acc[1][n], 0, 0, 0);
        }
        __syncthreads();
        if (kc < 7) { ah0 = an0; ah1 = an1; }
    }

    #pragma unroll
    for (int m = 0; m < 2; ++m)
        #pragma unroll
        for (int n = 0; n < 8; ++n) {
            float Cv = sC[n * 16 + l15];
            #pragma unroll
            for (int r = 0; r < 4; ++r) acc[m][n][r] = fmaf(-2.f, acc[m][n][r], Cv);
        }
    #pragma unroll
    for (int m = 0; m < 2; ++m)
        #pragma unroll
        for (int r = 0; r < 4; ++r) {
            float v = acc[m][0][r];
            #pragma unroll
            for (int n = 1; n < 8; ++n) v = fminf(v, acc[m][n][r]);
            v = fminf(v, __shfl_xor(v, 1, 64));
            v = fminf(v, __shfl_xor(v, 2, 64));
            v = fminf(v, __shfl_xor(v, 4, 64));
            v = fminf(v, __shfl_xor(v, 8, 64));
            int tloc = wv * 32 + m * 16 + qd * 4 + r;
            float thr = v + MARGIN;
            #pragma unroll
            for (int n = 0; n < 8; ++n) {
                float sv = acc[m][n][r];
                if (sv <= thr) {
                    int pos = atomicAdd(&lCnt[tloc], 1);
                    if (pos < 4) {
                        int2 e; e.x = __float_as_int(sv); e.y = c0 + n * 16 + l15;
                        lSlot[tloc][pos] = e;
                    }
                }
            }
        }
    __syncthreads();
    {
        int tloc = tid >> 1, half = tid & 1;
        size_t base = (size_t)(t0 + tloc) * 64 + slice * 4 + half * 2;
        int2 s0 = lSlot[tloc][half * 2];
        int2 s1 = lSlot[tloc][half * 2 + 1];
        if (half && lCnt[tloc] > 4) s1.y |= OVF_FLAG;   // slot 3 carries the flag
        gSlots[base]     = s0;
        gSlots[base + 1] = s1;
    }
}

// ---- exact np chain (per-lane, row from LDS copy of res) ----
static __device__ __forceinline__ float np_chain(const float* __restrict__ sRow,
                                                 const float* __restrict__ Ei,
                                                 int cc, float A, float C) {
    const float4* e = (const float4*)(Ei + (size_t)cc * DDIM);
    float a = 0.f;
    #pragma unroll 8
    for (int k = 0; k < 64; ++k) {
        float4 ev = e[k];
        const float4 rv = *(const float4*)(sRow + k * 4);
        a = fmaf(rv.x, ev.x, a); a = fmaf(rv.y, ev.y, a);
        a = fmaf(rv.z, ev.z, a); a = fmaf(rv.w, ev.w, a);
    }
    return __fadd_rn(fmaf(-2.f, a, A), C);
}

// ---- finalize: 1024 blocks x 4 waves x 4 tokens/wave ----
// RELEVANCE-GATED overflow (round-11 bug fix): a flagged slice triggers the
// full rescan only if min-over-its-4-slots <= thr+MARGIN. Proof of exactness:
// stored slots are within MARGIN of the slice's true min, so an irrelevant
// flagged slice (m4 > thr+MARGIN) has true min > thr -> contains no candidate;
// conversely true_min <= thr  =>  m4 <= thr+MARGIN -> gated in (superset of
// the proven round-10 gate). Flagged slots have sv > thr, so they can never
// be selected as winners. Outputs bit-identical.
__global__ __launch_bounds__(256) void vq_post(const float* __restrict__ resSrc,
                                               const float* __restrict__ Ei,
                                               const float* __restrict__ sseEi,
                                               float* __restrict__ res,
                                               float* __restrict__ zq,
                                               float* __restrict__ codes,
                                               float* __restrict__ lossPart,
                                               float* __restrict__ normA,
                                               unsigned short* __restrict__ resHp,
                                               unsigned short* __restrict__ zqb,
                                               const int2* __restrict__ gSlots,
                                               int iter) {
    __shared__ float sScr[4][4][256];
    const int tid = threadIdx.x;
    const int wv = tid >> 6, lane = tid & 63;
    const int g = lane >> 4, l15 = lane & 15;
    const int tb = blockIdx.x * 16 + wv * 4;
    float lsum = 0.f;

    // phase 1: all independent loads
    int2 sl[4]; float4 r4[4]; float4 zq4[4]; float A4[4];
    #pragma unroll
    for (int j = 0; j < 4; ++j) sl[j] = gSlots[(size_t)(tb + j) * 64 + lane];
    #pragma unroll
    for (int j = 0; j < 4; ++j)
        r4[j] = *(const float4*)(resSrc + (size_t)(tb + j) * DDIM + lane * 4);
    #pragma unroll
    for (int j = 0; j < 4; ++j) A4[j] = normA[tb + j];
    if (iter > 0) {
        #pragma unroll
        for (int j = 0; j < 4; ++j)
            zq4[j] = *(const float4*)(zq + (size_t)(tb + j) * DDIM + lane * 4);
    }

    // phase 2: winners
    int winner[4];
    #pragma unroll
    for (int j = 0; j < 4; ++j) {
        const float sv = __int_as_float(sl[j].x);
        float m4 = fminf(sv, __shfl_xor(sv, 1, 64));     // per-slice slot min
        m4 = fminf(m4, __shfl_xor(m4, 2, 64));
        float gm = m4;
        #pragma unroll
        for (int o = 32; o >= 4; o >>= 1) gm = fminf(gm, __shfl_xor(gm, o, 64));
        const float thr = gm + MARGIN;
        const bool flagged = ((lane & 3) == 3) && (sl[j].y & OVF_FLAG);
        const bool ovf = __any((flagged && m4 <= thr + MARGIN) ? 1 : 0);
        unsigned long long bal = __ballot((sv <= thr) ? 1 : 0);
        if (!ovf && __popcll(bal) == 1) {
            winner[j] = __shfl(sl[j].y, __ffsll(bal) - 1, 64);
        } else if (!ovf) {
            // lane-parallel exact eval of candidates
            *(float4*)(&sScr[wv][j][lane * 4]) = r4[j];
            const bool qal = (sv <= thr);
            const int cc = qal ? sl[j].y : 0;
            float s = np_chain(sScr[wv][j], Ei, cc, A4[j], sseEi[cc]);
            unsigned long long best = qal
                ? (((unsigned long long)__float_as_uint(s) << 32) | (unsigned)cc)
                : ~0ULL;
            #pragma unroll
            for (int o = 32; o >= 1; o >>= 1) {
                unsigned long long ot = __shfl_xor(best, o, 64);
                if (ot < best) best = ot;
            }
            winner[j] = (int)(unsigned)(best & 0xFFFFFFFFu);
        } else {
            // rare: full exact rescan
            *(float4*)(&sScr[wv][j][lane * 4]) = r4[j];
            unsigned long long best = ~0ULL;
            for (int cc = lane; cc < KCB; cc += 64) {
                float s = np_chain(sScr[wv][j], Ei, cc, A4[j], sseEi[cc]);
                unsigned long long key =
                    ((unsigned long long)__float_as_uint(s) << 32) | (unsigned)cc;
                if (key < best) best = key;
            }
            #pragma unroll
            for (int o = 32; o >= 1; o >>= 1) {
                unsigned long long ot = __shfl_xor(best, o, 64);
                if (ot < best) best = ot;
            }
            winner[j] = (int)(unsigned)(best & 0xFFFFFFFFu);
        }
    }
    #pragma unroll
    for (int j = 0; j < 4; ++j)
        if (lane == j) codes[(size_t)(tb + j) * NCB + iter] = (float)winner[j];

    // phase 3: concurrent gathers
    float4 q4[4];
    #pragma unroll
    for (int j = 0; j < 4; ++j)
        q4[j] = *(const float4*)(Ei + (size_t)winner[j] * DDIM + lane * 4);

    // phase 4: exact chain update + stores
    #pragma unroll
    for (int j = 0; j < 4; ++j) {
        const size_t go = (size_t)(tb + j) * DDIM + lane * 4;
        float4 rn4, zqi4;
        float tqx = q4[j].x - r4[j].x; zqi4.x = r4[j].x + tqx; rn4.x = r4[j].x - zqi4.x;
        float tqy = q4[j].y - r4[j].y; zqi4.y = r4[j].y + tqy; rn4.y = r4[j].y - zqi4.y;
        float tqz = q4[j].z - r4[j].z; zqi4.z = r4[j].z + tqz; rn4.z = r4[j].z - zqi4.z;
        float tqw = q4[j].w - r4[j].w; zqi4.w = r4[j].w + tqw; rn4.w = r4[j].w - zqi4.w;
        lsum = fmaf(tqx, tqx, lsum); lsum = fmaf(tqy, tqy, lsum);
        lsum = fmaf(tqz, tqz, lsum); lsum = fmaf(tqw, tqw, lsum);
        *(float4*)(res + go) = rn4;
        {
            unsigned short h[4] = { f2bf(rn4.x), f2bf(rn4.y), f2bf(rn4.z), f2bf(rn4.w) };
            *(ushort4*)(resHp + go) = *(ushort4*)h;
        }
        if (iter == 0) {
            *(float4*)(zq + go) = zqi4;
            unsigned short u[4] = { f2bf(zqi4.x), f2bf(zqi4.y), f2bf(zqi4.z), f2bf(zqi4.w) };
            *(ushort4*)(zqb + go) = *(ushort4*)u;
        } else {
            zq4[j].x += zqi4.x; zq4[j].y += zqi4.y;
            zq4[j].z += zqi4.z; zq4[j].w += zqi4.w;
            *(float4*)(zq + go) = zq4[j];
        }
        *(float4*)(&sScr[wv][j][lane * 4]) = rn4;
    }
    // phase 5: np-exact norms, 4 tokens in parallel (16-lane group g -> token tb+g)
    {
        const float* a = &sScr[wv][g][((l15 >> 3) << 7) + (l15 & 7)];
        float v = a[0];
        float r = __fmul_rn(v, v);
        #pragma unroll
        for (int k = 1; k < 16; ++k) { v = a[k * 8]; r = __fadd_rn(r, __fmul_rn(v, v)); }
        r = __fadd_rn(r, __shfl_xor(r, 1, 64));
        r = __fadd_rn(r, __shfl_xor(r, 2, 64));
        r = __fadd_rn(r, __shfl_xor(r, 4, 64));
        r = __fadd_rn(r, __shfl_xor(r, 8, 64));
        if (l15 == 0) normA[tb + g] = r;
    }
    #pragma unroll
    for (int o = 32; o >= 1; o >>= 1) lsum += __shfl_xor(lsum, o, 64);
    if (lane == 0) lossPart[iter * 4096 + blockIdx.x * 4 + wv] = lsum;
}

// ---- semantic head (round-6 proven 46us): 512 blocks = 256 grp x 2 halves
__global__ __launch_bounds__(256) void sem_mfma(const unsigned short* __restrict__ zqb,
                                                const float* __restrict__ tgt,
                                                const unsigned short* __restrict__ w1t,
                                                const float* __restrict__ b1,
                                                const unsigned short* __restrict__ w2t,
                                                const float* __restrict__ b2,
                                                float* __restrict__ semPart) {
    __shared__ uint4 sBq[2048];   // 32 KiB
    __shared__ uint4 sHq[2048];   // 32 KiB
    char* sBb = (char*)sBq;
    char* sHb = (char*)sHq;
    const int tid = threadIdx.x;
    const int wv = tid >> 6, lane = tid & 63;
    const int l15 = lane & 15, qd = lane >> 4;
    const int tb = (blockIdx.x >> 1) * 64;
    const int oh = blockIdx.x & 1;
    const int rs = tid >> 5, cs = tid & 31;
    const int swzs = (cs * 16) ^ ((rs & 7) << 4);

    #pragma unroll
    for (int j = 0; j < 8; ++j) {
        int r = j * 8 + rs;
        *(uint4*)(sHb + r * 512 + swzs) = *(const uint4*)(zqb + (size_t)(tb + r) * 256 + cs * 8);
    }
    __syncthreads();
    short8 az[8];
    {
        const int R = wv * 16 + l15;
        #pragma unroll
        for (int kc = 0; kc < 8; ++kc)
            az[kc] = *(const short8*)(sHb + R * 512 + ((kc * 64 + qd * 16) ^ ((R & 7) << 4)));
    }
    __syncthreads();

    #pragma unroll 1
    for (int s1 = 0; s1 < 4; ++s1) {
        #pragma unroll
        for (int j = 0; j < 8; ++j) {
            int r = j * 8 + rs;
            *(uint4*)(sBb + r * 512 + swzs) = *(const uint4*)(w1t + (size_t)(s1 * 64 + r) * 256 + cs * 8);
        }
        __syncthreads();
        f32x4 acc[4];
        #pragma unroll
        for (int n = 0; n < 4; ++n) acc[n] = (f32x4){0.f, 0.f, 0.f, 0.f};
        for (int kc = 0; kc < 8; ++kc) {
            #pragma unroll
            for (int n = 0; n < 4; ++n) {
                const int R = n * 16 + l15;
                short8 b = *(const short8*)(sBb + R * 512 + ((kc * 64 + qd * 16) ^ ((R & 7) << 4)));
                acc[n] = __builtin_amdgcn_mfma_f32_16x16x32_bf16(az[kc], b, acc[n], 0, 0, 0);
            }
        }
        #pragma unroll
        for (int n = 0; n < 4; ++n) {
            const int o = s1 * 64 + n * 16 + l15;
            const float b1v = b1[o];
            #pragma unroll
            for (int r = 0; r < 4; ++r) {
                float x = acc[n][r] + b1v;
                const int tr = wv * 16 + qd * 4 + r;
                *(unsigned short*)(sHb + tr * 512 + ((o * 2) ^ ((tr & 7) << 4))) =
                    f2bf(0.5f * x * (1.f + erff(x * 0.70710678f)));
            }
        }
        __syncthreads();
    }

    short8 ah[8];
    {
        const int R = wv * 16 + l15;
        #pragma unroll
        for (int kc = 0; kc < 8; ++kc)
            ah[kc] = *(const short8*)(sHb + R * 512 + ((kc * 64 + qd * 16) ^ ((R & 7) << 4)));
    }
    #pragma unroll
    for (int j = 0; j < 8; ++j) {
        int r = j * 8 + rs;
        *(uint4*)(sBb + r * 512 + swzs) = *(const uint4*)(w2t + (size_t)(oh * 512 + r) * 256 + cs * 8);
    }
    __syncthreads();

    float lsum = 0.f;
    #pragma unroll 1
    for (int s2 = 0; s2 < 8; ++s2) {
        const int gs = oh * 8 + s2;
        char* cb = (s2 & 1) ? sHb : sBb;
        char* nb = (s2 & 1) ? sBb : sHb;
        if (s2 < 7) {
            #pragma unroll
            for (int j = 0; j < 8; ++j) {
                int r = j * 8 + rs;
                *(uint4*)(nb + r * 512 + swzs) =
                    *(const uint4*)(w2t + (size_t)((gs + 1) * 64 + r) * 256 + cs * 8);
            }
        }
        float tg[4][4], b2v[4];
        #pragma unroll
        for (int n = 0; n < 4; ++n) {
            const int o = gs * 64 + n * 16 + l15;
            b2v[n] = b2[o];
            #pragma unroll
            for (int r = 0; r < 4; ++r)
                tg[n][r] = tgt[(size_t)(tb + wv * 16 + qd * 4 + r) * 1024 + o];
        }
        f32x4 acc[4];
        #pragma unroll
        for (int n = 0; n < 4; ++n) acc[n] = (f32x4){0.f, 0.f, 0.f, 0.f};
        for (int kc = 0; kc < 8; ++kc) {
            #pragma unroll
            for (int n = 0; n < 4; ++n) {
                const int R = n * 16 + l15;
                short8 b = *(const short8*)(cb + R * 512 + ((kc * 64 + qd * 16) ^ ((R & 7) << 4)));
                acc[n] = __builtin_amdgcn_mfma_f32_16x16x32_bf16(ah[kc], b, acc[n], 0, 0, 0);
            }
        }
        #pragma unroll
        for (int n = 0; n < 4; ++n)
            #pragma unroll
            for (int r = 0; r < 4; ++r) {
                float dv = (acc[n][r] + b2v[n]) - tg[n][r];
                lsum = fmaf(dv, dv, lsum);
            }
        __syncthreads();
    }
    #pragma unroll
    for (int o = 32; o >= 1; o >>= 1) lsum += __shfl_xor(lsum, o, 64);
    if (lane == 0) semPart[blockIdx.x * 4 + wv] = lsum;
}

// ---- loss finalize: vq (40960 wave partials) + semantic (2048 wave partials)
__global__ __launch_bounds__(256) void loss_final(const float* __restrict__ lossPart,
                                                  const float* __restrict__ semPart,
                                                  float* __restrict__ vql) {
    __shared__ float sRed[4], sRed2[4];
    float s = 0.f, q = 0.f;
    for (int i = threadIdx.x; i < 40960; i += 256) s += lossPart[i];
    for (int i = threadIdx.x; i < 2048; i += 256) q += semPart[i];
    #pragma unroll
    for (int o = 32; o >= 1; o >>= 1) { s += __shfl_xor(s, o, 64); q += __shfl_xor(q, o, 64); }
    if ((threadIdx.x & 63) == 0) { sRed[threadIdx.x >> 6] = s; sRed2[threadIdx.x >> 6] = q; }
    __syncthreads();
    if (threadIdx.x == 0) {
        vql[0] = (sRed[0] + sRed[1] + sRed[2] + sRed[3]) * (1.25f / 4194304.f);
        vql[1] = (sRed2[0] + sRed2[1] + sRed2[2] + sRed2[3]) * (1.0f / 16777216.f);
    }
}

extern "C" void kernel_launch(void* const* d_in, const int* in_sizes, int n_in,
                              void* d_out, int out_size, void* d_ws, size_t ws_size,
                              hipStream_t stream) {
    const float* z   = (const float*)d_in[0];
    const float* tgt = (const float*)d_in[1];
    const float* E   = (const float*)d_in[2];
    const float* W1  = (const float*)d_in[3];
    const float* b1  = (const float*)d_in[4];
    const float* W2  = (const float*)d_in[5];
    const float* b2  = (const float*)d_in[6];

    float* out   = (float*)d_out;
    float* zq    = out;
    float* codes = out + (size_t)NTOK * DDIM;
    float* vql   = codes + (size_t)NTOK * NCB;       // [vq_loss, semantic_loss]

    char* w = (char*)d_ws;
    float*          res   = (float*)(w);                         // 16 MiB
    unsigned short* resH  = (unsigned short*)(w + 16777216);     // 8 MiB
    float*          semPart=(float*)(w + 25165824);              // 8 KiB (old resL hole)
    unsigned short* Eh    = (unsigned short*)(w + 33554432);     // 10 MiB
    unsigned short* zqb   = (unsigned short*)(w + 54525952);     // 8 MiB
    int2*           gSlots= (int2*)(w + 62914560);               // 8 MiB
    float*          sseE  = (float*)(w + 73400320);              // 80 KiB (pad 128K)
    float*          normA = (float*)(w + 73531392);              // 64 KiB (pad 128K)
    float*          lossPart=(float*)(w + 73662464);             // 160 KiB (pad 256K)
    unsigned short* w1t   = (unsigned short*)(w + 73924608);     // 128 KiB
    unsigned short* w2t   = (unsigned short*)(w + 74055680);     // 512 KiB -> end 74579968

    prep_all<<<10496, 256, 0, stream>>>(E, z, W1, W2, sseE, normA, Eh, resH, w1t, w2t);
    for (int it = 0; it < NCB; ++it) {
        const float*          Ei    = E  + (size_t)it * KCB * DDIM;
        const unsigned short* Ehi   = Eh + (size_t)it * KCB * DDIM;
        const float*          sseEi = sseE + (size_t)it * KCB;
        const float* resSrc = (it == 0) ? z : res;
        vq_screen<<<2048, 256, 0, stream>>>(resH, Ehi, sseEi, gSlots);
        vq_post<<<1024, 256, 0, stream>>>(resSrc, Ei, sseEi, res, zq, codes, lossPart,
                                          normA, resH, zqb, gSlots, it);
        if (it == 0)
            sem_mfma<<<512, 256, 0, stream>>>(zqb, tgt, w1t, b1, w2t, b2, semPart);
    }
    loss_final<<<1, 256, 0, stream>>>(lossPart, semPart, vql);
}

// Round 13
// 888.085 us; speedup vs baseline: 3.2829x; 1.0244x over previous
//
#include <hip/hip_runtime.h>
#include <float.h>
#include <math.h>

#define NTOK 16384
#define KCB  2048
#define DDIM 256
#define NCB  10
// Screening margin. Screen is a SINGLE bf16 MFMA pass: per-dist error rms
// ~2.9e-5, code-pair difference rms ~4.1e-5 (dominated by bf16 rounding of
// res and E). Hoeffding with realized per-term bounds (sum b^2 ~ 5e-9):
// P(miss) <= exp(-2*(5e-4)^2/5e-9) = e^-100 per comparison -> safe over all
// 3.3e8 comparisons. Candidates within margin are exact-evaluated with the
// bit-identical np FMA chain, so outputs are exact regardless.
#define MARGIN 5.0e-4f
#define OVF_FLAG (1 << 30)   // overflow marker in slot-3 code field (codes<2048)

typedef __attribute__((ext_vector_type(8))) short  short8;
typedef __attribute__((ext_vector_type(4))) float  f32x4;

static __device__ __forceinline__ unsigned short f2bf(float f) {
    unsigned int b = __float_as_uint(f);
    unsigned int r = b + 0x7FFFu + ((b >> 16) & 1u);   // RNE
    return (unsigned short)(r >> 16);
}

// ================= fused prep =================
// blocks [0,5120): E conv x4 + np-exact row norms (LDS bounce);
// [5120,9216): z conv x4 + norms; [9216,9472): w1t; [9472,10496): w2t.
__global__ __launch_bounds__(256) void prep_all(const float* __restrict__ E,
                                                const float* __restrict__ z,
                                                const float* __restrict__ W1,
                                                const float* __restrict__ W2,
                                                float* __restrict__ sseE,
                                                float* __restrict__ normA,
                                                unsigned short* __restrict__ Eh,
                                                unsigned short* __restrict__ resH,
                                                unsigned short* __restrict__ w1t,
                                                unsigned short* __restrict__ w2t) {
    const int b = blockIdx.x;
    if (b < 9216) {
        __shared__ float sRow[4][260];    // +pad: spread 4 groups across banks
        const float* src; unsigned short* dst; float* ndst; int i, row0;
        if (b < 5120) { src = E; dst = Eh;   ndst = sseE;  i = b * 256 + threadIdx.x;          row0 = b * 4; }
        else          { src = z; dst = resH; ndst = normA; i = (b - 5120) * 256 + threadIdx.x; row0 = (b - 5120) * 4; }
        float4 f = *(const float4*)(src + (size_t)i * 4);
        unsigned short h[4] = { f2bf(f.x), f2bf(f.y), f2bf(f.z), f2bf(f.w) };
        *(ushort4*)(dst + (size_t)i * 4) = *(ushort4*)h;
        {
            int r = threadIdx.x >> 6, c = (threadIdx.x & 63) * 4;
            *(float4*)&sRow[r][c] = f;
        }
        __syncthreads();
        if (threadIdx.x < 64) {           // wave 0: 4 rows x 16-lane groups
            const int l15 = threadIdx.x & 15, g = threadIdx.x >> 4;
            const float* a = &sRow[g][((l15 >> 3) << 7) + (l15 & 7)];
            float v = a[0];
            float r = __fmul_rn(v, v);
            #pragma unroll
            for (int k = 1; k < 16; ++k) { v = a[k * 8]; r = __fadd_rn(r, __fmul_rn(v, v)); }
            r = __fadd_rn(r, __shfl_xor(r, 1, 64));
            r = __fadd_rn(r, __shfl_xor(r, 2, 64));
            r = __fadd_rn(r, __shfl_xor(r, 4, 64));
            r = __fadd_rn(r, __shfl_xor(r, 8, 64));
            if (l15 == 0) ndst[row0 + g] = r;
        }
    } else if (b < 9472) {
        int j = (b - 9216) * 256 + threadIdx.x;
        int n = j >> 8, k = j & 255;
        w1t[j] = f2bf(W1[k * 256 + n]);
    } else {
        int j = (b - 9472) * 256 + threadIdx.x;
        int n = j >> 8, k = j & 255;
        w2t[j] = f2bf(W2[k * 1024 + n]);
    }
}

// ---- MFMA screening: 2048 blocks, 128x128 tile, dbuf B, A-register
// prefetch, XCD-aware swizzle, gCnt/gMin eliminated (overflow flagged in
// slot-3 code bit 30). Bit-identical slot sets and MFMA values.
__global__ __launch_bounds__(256) void vq_screen(const unsigned short* __restrict__ resH,
                                                 const unsigned short* __restrict__ Ehi,
                                                 const float* __restrict__ sseEi,
                                                 int2* __restrict__ gSlots) {
    __shared__ unsigned short sBh[2][128 * 40];
    __shared__ float sC[128];
    __shared__ int   lCnt[128];
    __shared__ int2  lSlot[128][4];
    const int tid = threadIdx.x;
    const int wv = tid >> 6, lane = tid & 63;
    const int l15 = lane & 15, qd = lane >> 4;
    const int wid = (blockIdx.x & 7) * 256 + (blockIdx.x >> 3);   // XCD swizzle
    const int tile = wid >> 4, slice = wid & 15;
    const int t0 = tile * 128, c0 = slice * 128;

    if (tid < 128) { lCnt[tid] = 0; sC[tid] = sseEi[c0 + tid]; }
    {
        int2 inf; inf.x = 0x7F800000; inf.y = 0;
        ((int2*)lSlot)[tid] = inf; ((int2*)lSlot)[tid + 256] = inf;
    }

    f32x4 acc[2][8];
    #pragma unroll
    for (int m = 0; m < 2; ++m)
        #pragma unroll
        for (int n = 0; n < 8; ++n) acc[m][n] = (f32x4){0.f, 0.f, 0.f, 0.f};

    const size_t rowA0 = (size_t)(t0 + wv * 32 + l15) * 256 + qd * 8;
    short8 ah0 = *(const short8*)(resH + rowA0);
    short8 ah1 = *(const short8*)(resH + rowA0 + 16 * 256);
    #pragma unroll
    for (int jj = 0; jj < 2; ++jj) {
        int f = jj * 256 + tid;
        int r = f >> 2, cc = (f & 3) * 8;
        *(uint4*)(sBh[0] + r * 40 + cc) = *(const uint4*)(Ehi + (size_t)(c0 + r) * 256 + cc);
    }
    __syncthreads();

    for (int kc = 0; kc < 8; ++kc) {
        const int cur = kc & 1;
        short8 an0, an1;
        if (kc < 7) {
            const int dbn = (kc + 1) * 32;
            an0 = *(const short8*)(resH + rowA0 + dbn);
            an1 = *(const short8*)(resH + rowA0 + 16 * 256 + dbn);
            #pragma unroll
            for (int jj = 0; jj < 2; ++jj) {
                int f = jj * 256 + tid;
                int r = f >> 2, cc = (f & 3) * 8;
                *(uint4*)(sBh[cur ^ 1] + r * 40 + cc) =
                    *(const uint4*)(Ehi + (size_t)(c0 + r) * 256 + dbn + cc);
            }
        }
        #pragma unroll
        for (int n = 0; n < 8; ++n) {
            short8 bh = *(const short8*)(sBh[cur] + (n * 16 + l15) * 40 + qd * 8);
            acc[0][n] = __builtin_amdgcn_mfma_f32_16x16x32_bf16(ah0, bh, acc[0][n], 0, 0, 0);
            acc[1][n] = __builtin_amdgcn_mfma_f32_16x16x32_bf16(ah1, bh, acc[1][n], 0, 0, 0);
        }
        __syncthreads();
        if (kc < 7) { ah0 = an0; ah1 = an1; }
    }

    #pragma unroll
    for (int m = 0; m < 2; ++m)
        #pragma unroll
        for (int n = 0; n < 8; ++n) {
            float Cv = sC[n * 16 + l15];
            #pragma unroll
            for (int r = 0; r < 4; ++r) acc[m][n][r] = fmaf(-2.f, acc[m][n][r], Cv);
        }
    #pragma unroll
    for (int m = 0; m < 2; ++m)
        #pragma unroll
        for (int r = 0; r < 4; ++r) {
            float v = acc[m][0][r];
            #pragma unroll
            for (int n = 1; n < 8; ++n) v = fminf(v, acc[m][n][r]);
            v = fminf(v, __shfl_xor(v, 1, 64));
            v = fminf(v, __shfl_xor(v, 2, 64));
            v = fminf(v, __shfl_xor(v, 4, 64));
            v = fminf(v, __shfl_xor(v, 8, 64));
            int tloc = wv * 32 + m * 16 + qd * 4 + r;
            float thr = v + MARGIN;
            #pragma unroll
            for (int n = 0; n < 8; ++n) {
                float sv = acc[m][n][r];
                if (sv <= thr) {
                    int pos = atomicAdd(&lCnt[tloc], 1);
                    if (pos < 4) {
                        int2 e; e.x = __float_as_int(sv); e.y = c0 + n * 16 + l15;
                        lSlot[tloc][pos] = e;
                    }
                }
            }
        }
    __syncthreads();
    {
        int tloc = tid >> 1, half = tid & 1;
        size_t base = (size_t)(t0 + tloc) * 64 + slice * 4 + half * 2;
        int2 s0 = lSlot[tloc][half * 2];
        int2 s1 = lSlot[tloc][half * 2 + 1];
        if (half && lCnt[tloc] > 4) s1.y |= OVF_FLAG;   // slot 3 carries the flag
        gSlots[base]     = s0;
        gSlots[base + 1] = s1;
    }
}

// ---- exact np chain (per-lane, row from LDS copy of res) ----
static __device__ __forceinline__ float np_chain(const float* __restrict__ sRow,
                                                 const float* __restrict__ Ei,
                                                 int cc, float A, float C) {
    const float4* e = (const float4*)(Ei + (size_t)cc * DDIM);
    float a = 0.f;
    #pragma unroll 8
    for (int k = 0; k < 64; ++k) {
        float4 ev = e[k];
        const float4 rv = *(const float4*)(sRow + k * 4);
        a = fmaf(rv.x, ev.x, a); a = fmaf(rv.y, ev.y, a);
        a = fmaf(rv.z, ev.z, a); a = fmaf(rv.w, ev.w, a);
    }
    return __fadd_rn(fmaf(-2.f, a, A), C);
}

// ---- finalize: 1024 blocks x 4 waves x 4 tokens/wave ----
// Relevance-gated overflow (proven r12). Last-iteration dead stores skipped:
// res/resH/norm feed only the next iteration, which doesn't exist for it=9.
__global__ __launch_bounds__(256) void vq_post(const float* __restrict__ resSrc,
                                               const float* __restrict__ Ei,
                                               const float* __restrict__ sseEi,
                                               float* __restrict__ res,
                                               float* __restrict__ zq,
                                               float* __restrict__ codes,
                                               float* __restrict__ lossPart,
                                               float* __restrict__ normA,
                                               unsigned short* __restrict__ resHp,
                                               unsigned short* __restrict__ zqb,
                                               const int2* __restrict__ gSlots,
                                               int iter) {
    __shared__ float sScr[4][4][256];
    const int tid = threadIdx.x;
    const int wv = tid >> 6, lane = tid & 63;
    const int g = lane >> 4, l15 = lane & 15;
    const int tb = blockIdx.x * 16 + wv * 4;
    const bool notLast = (iter != NCB - 1);
    float lsum = 0.f;

    // phase 1: all independent loads
    int2 sl[4]; float4 r4[4]; float4 zq4[4]; float A4[4];
    #pragma unroll
    for (int j = 0; j < 4; ++j) sl[j] = gSlots[(size_t)(tb + j) * 64 + lane];
    #pragma unroll
    for (int j = 0; j < 4; ++j)
        r4[j] = *(const float4*)(resSrc + (size_t)(tb + j) * DDIM + lane * 4);
    #pragma unroll
    for (int j = 0; j < 4; ++j) A4[j] = normA[tb + j];
    if (iter > 0) {
        #pragma unroll
        for (int j = 0; j < 4; ++j)
            zq4[j] = *(const float4*)(zq + (size_t)(tb + j) * DDIM + lane * 4);
    }

    // phase 2: winners
    int winner[4];
    #pragma unroll
    for (int j = 0; j < 4; ++j) {
        const float sv = __int_as_float(sl[j].x);
        float m4 = fminf(sv, __shfl_xor(sv, 1, 64));     // per-slice slot min
        m4 = fminf(m4, __shfl_xor(m4, 2, 64));
        float gm = m4;
        #pragma unroll
        for (int o = 32; o >= 4; o >>= 1) gm = fminf(gm, __shfl_xor(gm, o, 64));
        const float thr = gm + MARGIN;
        const bool flagged = ((lane & 3) == 3) && (sl[j].y & OVF_FLAG);
        const bool ovf = __any((flagged && m4 <= thr + MARGIN) ? 1 : 0);
        unsigned long long bal = __ballot((sv <= thr) ? 1 : 0);
        if (!ovf && __popcll(bal) == 1) {
            winner[j] = __shfl(sl[j].y, __ffsll(bal) - 1, 64);
        } else if (!ovf) {
            // lane-parallel exact eval of candidates
            *(float4*)(&sScr[wv][j][lane * 4]) = r4[j];
            const bool qal = (sv <= thr);
            const int cc = qal ? sl[j].y : 0;
            float s = np_chain(sScr[wv][j], Ei, cc, A4[j], sseEi[cc]);
            unsigned long long best = qal
                ? (((unsigned long long)__float_as_uint(s) << 32) | (unsigned)cc)
                : ~0ULL;
            #pragma unroll
            for (int o = 32; o >= 1; o >>= 1) {
                unsigned long long ot = __shfl_xor(best, o, 64);
                if (ot < best) best = ot;
            }
            winner[j] = (int)(unsigned)(best & 0xFFFFFFFFu);
        } else {
            // rare: full exact rescan
            *(float4*)(&sScr[wv][j][lane * 4]) = r4[j];
            unsigned long long best = ~0ULL;
            for (int cc = lane; cc < KCB; cc += 64) {
                float s = np_chain(sScr[wv][j], Ei, cc, A4[j], sseEi[cc]);
                unsigned long long key =
                    ((unsigned long long)__float_as_uint(s) << 32) | (unsigned)cc;
                if (key < best) best = key;
            }
            #pragma unroll
            for (int o = 32; o >= 1; o >>= 1) {
                unsigned long long ot = __shfl_xor(best, o, 64);
                if (ot < best) best = ot;
            }
            winner[j] = (int)(unsigned)(best & 0xFFFFFFFFu);
        }
    }
    #pragma unroll
    for (int j = 0; j < 4; ++j)
        if (lane == j) codes[(size_t)(tb + j) * NCB + iter] = (float)winner[j];

    // phase 3: concurrent gathers
    float4 q4[4];
    #pragma unroll
    for (int j = 0; j < 4; ++j)
        q4[j] = *(const float4*)(Ei + (size_t)winner[j] * DDIM + lane * 4);

    // phase 4: exact chain update + stores
    #pragma unroll
    for (int j = 0; j < 4; ++j) {
        const size_t go = (size_t)(tb + j) * DDIM + lane * 4;
        float4 rn4, zqi4;
        float tqx = q4[j].x - r4[j].x; zqi4.x = r4[j].x + tqx; rn4.x = r4[j].x - zqi4.x;
        float tqy = q4[j].y - r4[j].y; zqi4.y = r4[j].y + tqy; rn4.y = r4[j].y - zqi4.y;
        float tqz = q4[j].z - r4[j].z; zqi4.z = r4[j].z + tqz; rn4.z = r4[j].z - zqi4.z;
        float tqw = q4[j].w - r4[j].w; zqi4.w = r4[j].w + tqw; rn4.w = r4[j].w - zqi4.w;
        lsum = fmaf(tqx, tqx, lsum); lsum = fmaf(tqy, tqy, lsum);
        lsum = fmaf(tqz, tqz, lsum); lsum = fmaf(tqw, tqw, lsum);
        if (notLast) {
            *(float4*)(res + go) = rn4;
            unsigned short h[4] = { f2bf(rn4.x), f2bf(rn4.y), f2bf(rn4.z), f2bf(rn4.w) };
            *(ushort4*)(resHp + go) = *(ushort4*)h;
            *(float4*)(&sScr[wv][j][lane * 4]) = rn4;
        }
        if (iter == 0) {
            *(float4*)(zq + go) = zqi4;
            unsigned short u[4] = { f2bf(zqi4.x), f2bf(zqi4.y), f2bf(zqi4.z), f2bf(zqi4.w) };
            *(ushort4*)(zqb + go) = *(ushort4*)u;
        } else {
            zq4[j].x += zqi4.x; zq4[j].y += zqi4.y;
            zq4[j].z += zqi4.z; zq4[j].w += zqi4.w;
            *(float4*)(zq + go) = zq4[j];
        }
    }
    // phase 5: np-exact norms for next iter (skipped on last iter)
    if (notLast) {
        const float* a = &sScr[wv][g][((l15 >> 3) << 7) + (l15 & 7)];
        float v = a[0];
        float r = __fmul_rn(v, v);
        #pragma unroll
        for (int k = 1; k < 16; ++k) { v = a[k * 8]; r = __fadd_rn(r, __fmul_rn(v, v)); }
        r = __fadd_rn(r, __shfl_xor(r, 1, 64));
        r = __fadd_rn(r, __shfl_xor(r, 2, 64));
        r = __fadd_rn(r, __shfl_xor(r, 4, 64));
        r = __fadd_rn(r, __shfl_xor(r, 8, 64));
        if (l15 == 0) normA[tb + g] = r;
    }
    #pragma unroll
    for (int o = 32; o >= 1; o >>= 1) lsum += __shfl_xor(lsum, o, 64);
    if (lane == 0) lossPart[iter * 4096 + blockIdx.x * 4 + wv] = lsum;
}

// ---- semantic head (round-6 proven 46us): 512 blocks = 256 grp x 2 halves
__global__ __launch_bounds__(256) void sem_mfma(const unsigned short* __restrict__ zqb,
                                                const float* __restrict__ tgt,
                                                const unsigned short* __restrict__ w1t,
                                                const float* __restrict__ b1,
                                                const unsigned short* __restrict__ w2t,
                                                const float* __restrict__ b2,
                                                float* __restrict__ semPart) {
    __shared__ uint4 sBq[2048];   // 32 KiB
    __shared__ uint4 sHq[2048];   // 32 KiB
    char* sBb = (char*)sBq;
    char* sHb = (char*)sHq;
    const int tid = threadIdx.x;
    const int wv = tid >> 6, lane = tid & 63;
    const int l15 = lane & 15, qd = lane >> 4;
    const int tb = (blockIdx.x >> 1) * 64;
    const int oh = blockIdx.x & 1;
    const int rs = tid >> 5, cs = tid & 31;
    const int swzs = (cs * 16) ^ ((rs & 7) << 4);

    #pragma unroll
    for (int j = 0; j < 8; ++j) {
        int r = j * 8 + rs;
        *(uint4*)(sHb + r * 512 + swzs) = *(const uint4*)(zqb + (size_t)(tb + r) * 256 + cs * 8);
    }
    __syncthreads();
    short8 az[8];
    {
        const int R = wv * 16 + l15;
        #pragma unroll
        for (int kc = 0; kc < 8; ++kc)
            az[kc] = *(const short8*)(sHb + R * 512 + ((kc * 64 + qd * 16) ^ ((R & 7) << 4)));
    }
    __syncthreads();

    #pragma unroll 1
    for (int s1 = 0; s1 < 4; ++s1) {
        #pragma unroll
        for (int j = 0; j < 8; ++j) {
            int r = j * 8 + rs;
            *(uint4*)(sBb + r * 512 + swzs) = *(const uint4*)(w1t + (size_t)(s1 * 64 + r) * 256 + cs * 8);
        }
        __syncthreads();
        f32x4 acc[4];
        #pragma unroll
        for (int n = 0; n < 4; ++n) acc[n] = (f32x4){0.f, 0.f, 0.f, 0.f};
        for (int kc = 0; kc < 8; ++kc) {
            #pragma unroll
            for (int n = 0; n < 4; ++n) {
                const int R = n * 16 + l15;
                short8 b = *(const short8*)(sBb + R * 512 + ((kc * 64 + qd * 16) ^ ((R & 7) << 4)));
                acc[n] = __builtin_amdgcn_mfma_f32_16x16x32_bf16(az[kc], b, acc[n], 0, 0, 0);
            }
        }
        #pragma unroll
        for (int n = 0; n < 4; ++n) {
            const int o = s1 * 64 + n * 16 + l15;
            const float b1v = b1[o];
            #pragma unroll
            for (int r = 0; r < 4; ++r) {
                float x = acc[n][r] + b1v;
                const int tr = wv * 16 + qd * 4 + r;
                *(unsigned short*)(sHb + tr * 512 + ((o * 2) ^ ((tr & 7) << 4))) =
                    f2bf(0.5f * x * (1.f + erff(x * 0.70710678f)));
            }
        }
        __syncthreads();
    }

    short8 ah[8];
    {
        const int R = wv * 16 + l15;
        #pragma unroll
        for (int kc = 0; kc < 8; ++kc)
            ah[kc] = *(const short8*)(sHb + R * 512 + ((kc * 64 + qd * 16) ^ ((R & 7) << 4)));
    }
    #pragma unroll
    for (int j = 0; j < 8; ++j) {
        int r = j * 8 + rs;
        *(uint4*)(sBb + r * 512 + swzs) = *(const uint4*)(w2t + (size_t)(oh * 512 + r) * 256 + cs * 8);
    }
    __syncthreads();

    float lsum = 0.f;
    #pragma unroll 1
    for (int s2 = 0; s2 < 8; ++s2) {
        const int gs = oh * 8 + s2;
        char* cb = (s2 & 1) ? sHb : sBb;
        char* nb = (s2 & 1) ? sBb : sHb;
        if (s2 < 7) {
            #pragma unroll
            for (int j = 0; j < 8; ++j) {
                int r = j * 8 + rs;
                *(uint4*)(nb + r * 512 + swzs) =
                    *(const uint4*)(w2t + (size_t)((gs + 1) * 64 + r) * 256 + cs * 8);
            }
        }
        float tg[4][4], b2v[4];
        #pragma unroll
        for (int n = 0; n < 4; ++n) {
            const int o = gs * 64 + n * 16 + l15;
            b2v[n] = b2[o];
            #pragma unroll
            for (int r = 0; r < 4; ++r)
                tg[n][r] = tgt[(size_t)(tb + wv * 16 + qd * 4 + r) * 1024 + o];
        }
        f32x4 acc[4];
        #pragma unroll
        for (int n = 0; n < 4; ++n) acc[n] = (f32x4){0.f, 0.f, 0.f, 0.f};
        for (int kc = 0; kc < 8; ++kc) {
            #pragma unroll
            for (int n = 0; n < 4; ++n) {
                const int R = n * 16 + l15;
                short8 b = *(const short8*)(cb + R * 512 + ((kc * 64 + qd * 16) ^ ((R & 7) << 4)));
                acc[n] = __builtin_amdgcn_mfma_f32_16x16x32_bf16(ah[kc], b, acc[n], 0, 0, 0);
            }
        }
        #pragma unroll
        for (int n = 0; n < 4; ++n)
            #pragma unroll
            for (int r = 0; r < 4; ++r) {
                float dv = (acc[n][r] + b2v[n]) - tg[n][r];
                lsum = fmaf(dv, dv, lsum);
            }
        __syncthreads();
    }
    #pragma unroll
    for (int o = 32; o >= 1; o >>= 1) lsum += __shfl_xor(lsum, o, 64);
    if (lane == 0) semPart[blockIdx.x * 4 + wv] = lsum;
}

// ---- loss finalize: vq (40960 wave partials) + semantic (2048 wave partials)
__global__ __launch_bounds__(256) void loss_final(const float* __restrict__ lossPart,
                                                  const float* __restrict__ semPart,
                                                  float* __restrict__ vql) {
    __shared__ float sRed[4], sRed2[4];
    const float4* lp4 = (const float4*)lossPart;
    const float4* sp4 = (const float4*)semPart;
    float s = 0.f, q = 0.f;
    for (int i = threadIdx.x; i < 10240; i += 256) {
        float4 v = lp4[i];
        s += v.x + v.y + v.z + v.w;
    }
    {
        float4 v = sp4[threadIdx.x];
        q = v.x + v.y + v.z + v.w;
        v = sp4[threadIdx.x + 256];
        q += v.x + v.y + v.z + v.w;
    }
    #pragma unroll
    for (int o = 32; o >= 1; o >>= 1) { s += __shfl_xor(s, o, 64); q += __shfl_xor(q, o, 64); }
    if ((threadIdx.x & 63) == 0) { sRed[threadIdx.x >> 6] = s; sRed2[threadIdx.x >> 6] = q; }
    __syncthreads();
    if (threadIdx.x == 0) {
        vql[0] = (sRed[0] + sRed[1] + sRed[2] + sRed[3]) * (1.25f / 4194304.f);
        vql[1] = (sRed2[0] + sRed2[1] + sRed2[2] + sRed2[3]) * (1.0f / 16777216.f);
    }
}

extern "C" void kernel_launch(void* const* d_in, const int* in_sizes, int n_in,
                              void* d_out, int out_size, void* d_ws, size_t ws_size,
                              hipStream_t stream) {
    const float* z   = (const float*)d_in[0];
    const float* tgt = (const float*)d_in[1];
    const float* E   = (const float*)d_in[2];
    const float* W1  = (const float*)d_in[3];
    const float* b1  = (const float*)d_in[4];
    const float* W2  = (const float*)d_in[5];
    const float* b2  = (const float*)d_in[6];

    float* out   = (float*)d_out;
    float* zq    = out;
    float* codes = out + (size_t)NTOK * DDIM;
    float* vql   = codes + (size_t)NTOK * NCB;       // [vq_loss, semantic_loss]

    char* w = (char*)d_ws;
    float*          res   = (float*)(w);                         // 16 MiB
    unsigned short* resH  = (unsigned short*)(w + 16777216);     // 8 MiB
    float*          semPart=(float*)(w + 25165824);              // 8 KiB (old resL hole)
    unsigned short* Eh    = (unsigned short*)(w + 33554432);     // 10 MiB
    unsigned short* zqb   = (unsigned short*)(w + 54525952);     // 8 MiB
    int2*           gSlots= (int2*)(w + 62914560);               // 8 MiB
    float*          sseE  = (float*)(w + 73400320);              // 80 KiB (pad 128K)
    float*          normA = (float*)(w + 73531392);              // 64 KiB (pad 128K)
    float*          lossPart=(float*)(w + 73662464);             // 160 KiB (pad 256K)
    unsigned short* w1t   = (unsigned short*)(w + 73924608);     // 128 KiB
    unsigned short* w2t   = (unsigned short*)(w + 74055680);     // 512 KiB -> end 74579968

    prep_all<<<10496, 256, 0, stream>>>(E, z, W1, W2, sseE, normA, Eh, resH, w1t, w2t);
    for (int it = 0; it < NCB; ++it) {
        const float*          Ei    = E  + (size_t)it * KCB * DDIM;
        const unsigned short* Ehi   = Eh + (size_t)it * KCB * DDIM;
        const float*          sseEi = sseE + (size_t)it * KCB;
        const float* resSrc = (it == 0) ? z : res;
        vq_screen<<<2048, 256, 0, stream>>>(resH, Ehi, sseEi, gSlots);
        vq_post<<<1024, 256, 0, stream>>>(resSrc, Ei, sseEi, res, zq, codes, lossPart,
                                          normA, resH, zqb, gSlots, it);
        if (it == 0)
            sem_mfma<<<512, 256, 0, stream>>>(zqb, tgt, w1t, b1, w2t, b2, semPart);
    }
    loss_final<<<1, 256, 0, stream>>>(lossPart, semPart, vql);
}